// Round 5
// baseline (2193.887 us; speedup 1.0000x reference)
//
#include <hip/hip_runtime.h>
#include <stdint.h>

#define NPTS  8192
#define NB    4
#define KNN   20
#define NROWS (NB * NPTS)        // 32768
#define MTOTF 655360.0f          // NROWS * KNN
#define WPB   8                  // waves per block
#define BLK   (WPB * 64)         // 512 threads
#define SLICE (NPTS / WPB)       // fallback kernel slice
#define LSTR  (KNN + 1)
#define CAP   12                 // push-buffer slots per (wave,lane)
#define NEG_INF -3.0e38f

// ---- spatial grid ----
#define GDIM  32
#define BINS  (GDIM * GDIM * GDIM)     // 32768 cells
#define HCELL 0.25f
#define INVH  4.0f
#define XMIN  -4.0f
#define VLIM  4096                     // bbox cell-volume above which -> linear scan

__device__ __forceinline__ float med3f(float a, float b, float c) {
    return __builtin_amdgcn_fmed3f(a, b, c);
}

// Monotone float<->uint encoding so LDS atomicMax works as float-max (any sign).
__device__ __forceinline__ unsigned enc_f(float f) {
    unsigned u = __float_as_uint(f);
    return (u & 0x80000000u) ? ~u : (u | 0x80000000u);
}
__device__ __forceinline__ float dec_f(unsigned u) {
    return __uint_as_float((u & 0x80000000u) ? (u & 0x7fffffffu) : ~u);
}

// Insert t into descending top-KNN list (arr[0] = largest t = nearest point).
// Dropping off the bottom is always exact: 20 larger witnesses exist.
__device__ __forceinline__ void insert_t(float arr[KNN], float t) {
#pragma unroll
    for (int j = KNN - 1; j > 0; --j) arr[j] = med3f(t, arr[j - 1], arr[j]);
    arr[0] = fmaxf(arr[0], t);
}

// Chunk-skippable flush (4 slots per uniform test); publishes new 20th-best.
__device__ __forceinline__ void flush_sk(float arr[KNN], int& cnt,
    const float* bufw, int lane, unsigned* threshS) {
#pragma unroll
    for (int s0 = 0; s0 < CAP; s0 += 4) {
        if (__any(cnt > s0)) {
#pragma unroll
            for (int s = s0; s < s0 + 4; ++s) {
                const float v = bufw[s * 64 + lane];
                insert_t(arr, (s < cnt) ? v : NEG_INF);
            }
        }
    }
    cnt = 0;
    atomicMax(&threshS[lane], enc_f(arr[KNN - 1]));
}

// 5-bit Morton spread: bit k -> bit 3k.
__device__ __forceinline__ unsigned mort5(unsigned v) {
    v &= 31u;
    v = (v | (v << 8)) & 0x100Fu;
    v = (v | (v << 4)) & 0x10C3u;
    v = (v | (v << 2)) & 0x1249u;
    return v;
}
__device__ __forceinline__ int mort3(int cx, int cy, int cz) {
    return (int)(mort5(cx) | (mort5(cy) << 1) | (mort5(cz) << 2));
}
__device__ __forceinline__ int cellc(float v) {
    int c = (int)floorf((v - XMIN) * INVH);
    return min(max(c, 0), GDIM - 1);
}

// Shared tail: caller holds merged descending-t list for output row `row`.
// t = p.q - |q|^2/2, d2 = |p|^2 - 2t  (arr[0] = largest t = nearest).
__device__ __forceinline__ void finalize_row(
    float arr[KNN], float px, float py, float pz, int row, int lane,
    float* __restrict__ kmaxA, float* __restrict__ kminA, float* __restrict__ acc)
{
    const float pn2 = px * px + py * py + pz * pz;
    float sum = 0.f, sum2 = 0.f, dmin = 0.f, dmax = 0.f;
#pragma unroll
    for (int k = 0; k < KNN; ++k) {
        float d2 = fmaxf(fmaf(-2.f, arr[k], pn2), 0.f);
        float d = sqrtf(d2);
        sum += d; sum2 += d2;
        if (k == 0) dmin = d;
        dmax = d;
    }
    kmaxA[row] = dmax;
    kminA[row] = dmin;
#pragma unroll
    for (int o = 32; o; o >>= 1) {
        sum  += __shfl_down(sum,  o, 64);
        sum2 += __shfl_down(sum2, o, 64);
    }
    if (lane == 0) { atomicAdd(acc, sum); atomicAdd(acc + 1, sum2); }
}

// ---- sort infrastructure ----

// K_A: cell ids + per-batch histogram (counts live in `cursor`, pre-zeroed).
__global__ __launch_bounds__(256) void cell_kernel(
    const float* __restrict__ x, int* __restrict__ cellid,
    int* __restrict__ counts, float* __restrict__ acc)
{
    const int i = blockIdx.x * 256 + threadIdx.x;    // 0..32767
    const int b = i >> 13;
    const int n = i & (NPTS - 1);
    const float* xb = x + b * 3 * NPTS;
    const int m = mort3(cellc(xb[n]), cellc(xb[NPTS + n]), cellc(xb[2 * NPTS + n]));
    cellid[i] = m;
    atomicAdd(&counts[b * BINS + m], 1);
    if (i < 2) acc[i] = 0.f;
}

// K_B: per-batch exclusive scan of 32768 bins (1 block/batch, 1024 threads,
// 32 bins/thread). Writes cellStart[b][c] and re-inits cursor to starts.
__global__ __launch_bounds__(1024) void scan_kernel(
    int* __restrict__ cursor, int* __restrict__ cellStart)
{
    __shared__ int sums[1024];
    const int b = blockIdx.x;
    const int t = threadIdx.x;
    const int base = b * BINS + t * 32;
    int c[32]; int s = 0;
#pragma unroll
    for (int k = 0; k < 32; ++k) { c[k] = cursor[base + k]; s += c[k]; }
    sums[t] = s;
    __syncthreads();
    for (int off = 1; off < 1024; off <<= 1) {
        const int v = (t >= off) ? sums[t - off] : 0;
        __syncthreads();
        sums[t] += v;
        __syncthreads();
    }
    int run = sums[t] - s;                 // exclusive prefix
#pragma unroll
    for (int k = 0; k < 32; ++k) {
        cellStart[b * (BINS + 1) + t * 32 + k] = run;
        cursor[base + k] = run;
        run += c[k];
    }
    if (t == 1023) cellStart[b * (BINS + 1) + BINS] = run;   // = NPTS
}

// K_C: scatter points into Morton-sorted order; precompute w = -|q|^2/2.
__global__ __launch_bounds__(256) void scatter_kernel(
    const float* __restrict__ x, const int* __restrict__ cellid,
    int* __restrict__ cursor, float4* __restrict__ sorted4, int* __restrict__ perm)
{
    const int i = blockIdx.x * 256 + threadIdx.x;
    const int b = i >> 13;
    const int n = i & (NPTS - 1);
    const float* xb = x + b * 3 * NPTS;
    const float qx = xb[n], qy = xb[NPTS + n], qz = xb[2 * NPTS + n];
    const int pos = atomicAdd(&cursor[b * BINS + cellid[i]], 1);
    sorted4[b * NPTS + pos] = make_float4(qx, qy, qz, -0.5f * (qx * qx + qy * qy + qz * qz));
    perm[b * NPTS + pos] = i;
}

// ---- K_D: grid kNN. One block per 64 Morton-consecutive rows. Waves walk
// cell shells around the group bbox (round-robin cells), streaming candidates
// through the verified R2 machinery (scalar loads, branchless push, chunked
// flush, shared LDS threshold). Exact stop: after completing shells 0..s,
// any unseen point is >= s*HCELL away; stop when all rows' d20 <= s*HCELL. ----

#define PROCESS_CELL(cx_, cy_, cz_)                                             \
    if (((slot++) & 7) == wave) {                                               \
        const int m_ = mort3(cx_, cy_, cz_);                                    \
        const int cs_ = cellStart[csBase + m_];                                 \
        const int ce_ = cellStart[csBase + m_ + 1];                             \
        for (int ii_ = cs_; ii_ < ce_; ++ii_) {                                 \
            const float4 q_ = sorted4[sBase + ii_];                             \
            const float t_ = fmaf(q_.x, px, fmaf(q_.y, py, fmaf(q_.z, pz, q_.w))); \
            bufw[cnt * 64 + lane] = t_;                                         \
            cnt += (t_ > th);                                                   \
            if (__any(cnt == CAP)) {                                            \
                flush_sk(arr, cnt, bufw, lane, threshS);                        \
                th = dec_f(*(volatile unsigned*)(threshS + lane));              \
            }                                                                   \
        }                                                                       \
    }

__global__ __launch_bounds__(BLK, 8) void knn_grid_kernel(
    const float4* __restrict__ sorted4, const int* __restrict__ perm,
    const int* __restrict__ cellStart,
    float* __restrict__ kmaxA, float* __restrict__ kminA, float* __restrict__ acc)
{
    __shared__ float shmem[WPB * CAP * 64];        // push buffers; aliased by merge lists
    __shared__ unsigned threshS[64];

    const int tid  = threadIdx.x;
    const int lane = tid & 63;
    const int wave = __builtin_amdgcn_readfirstlane(tid >> 6);
    const int g    = (int)((blockIdx.x * 331u) & 511u);   // spread heavy groups
    const int base = g * 64;                  // sorted row base
    const int b    = g >> 7;                  // 128 groups per batch
    const int csBase = b * (BINS + 1);
    const int sBase  = b * NPTS;

    const float4 P = sorted4[base + lane];    // coalesced; same rows for all waves
    const float px = P.x, py = P.y, pz = P.z;
    const float pn2 = -2.f * P.w;

    // group cell bbox (identical in every wave)
    int cx = cellc(px), cy = cellc(py), cz = cellc(pz);
    int bx0 = cx, bx1 = cx, by0 = cy, by1 = cy, bz0 = cz, bz1 = cz;
#pragma unroll
    for (int o = 32; o; o >>= 1) {
        bx0 = min(bx0, __shfl_xor(bx0, o, 64)); bx1 = max(bx1, __shfl_xor(bx1, o, 64));
        by0 = min(by0, __shfl_xor(by0, o, 64)); by1 = max(by1, __shfl_xor(by1, o, 64));
        bz0 = min(bz0, __shfl_xor(bz0, o, 64)); bz1 = max(bz1, __shfl_xor(bz1, o, 64));
    }

    if (tid < 64) threshS[tid] = enc_f(NEG_INF);
    float arr[KNN];
#pragma unroll
    for (int j = 0; j < KNN; ++j) arr[j] = NEG_INF;
    float* bufw = shmem + wave * (CAP * 64);
    int cnt = 0;
    float th = NEG_INF;
    __syncthreads();

    const int vol = (bx1 - bx0 + 1) * (by1 - by0 + 1) * (bz1 - bz0 + 1);

    if (vol > VLIM) {
        // pathological Morton-boundary group: linear full-batch scan (exact)
        const int i0 = wave * (NPTS / WPB);
        int slot = 0; (void)slot;
        for (int ii_ = i0; ii_ < i0 + NPTS / WPB; ++ii_) {
            const float4 q_ = sorted4[sBase + ii_];
            const float t_ = fmaf(q_.x, px, fmaf(q_.y, py, fmaf(q_.z, pz, q_.w)));
            bufw[cnt * 64 + lane] = t_;
            cnt += (t_ > th);
            if (__any(cnt == CAP)) {
                flush_sk(arr, cnt, bufw, lane, threshS);
                th = dec_f(*(volatile unsigned*)(threshS + lane));
            }
        }
        if (__any(cnt > 0)) flush_sk(arr, cnt, bufw, lane, threshS);
        __syncthreads();
    } else {
        for (int s = 0; s < GDIM; ++s) {
            const int x0 = max(bx0 - s, 0), x1 = min(bx1 + s, GDIM - 1);
            const int y0 = max(by0 - s, 0), y1 = min(by1 + s, GDIM - 1);
            const int z0 = max(bz0 - s, 0), z1 = min(bz1 + s, GDIM - 1);
            int slot = 0;
            for (int zc = z0; zc <= z1; ++zc) {
                int dz = max(bz0 - zc, zc - bz1); dz = max(dz, 0);
                for (int yc = y0; yc <= y1; ++yc) {
                    int dy = max(by0 - yc, yc - by1); dy = max(dy, 0);
                    const int dzy = max(dz, dy);
                    if (dzy == s) {
                        for (int xc = x0; xc <= x1; ++xc) { PROCESS_CELL(xc, yc, zc) }
                    } else {
                        const int xa = bx0 - s, xb2 = bx1 + s;   // dx==s faces only
                        if (xa >= 0)        { PROCESS_CELL(xa,  yc, zc) }
                        if (xb2 <= GDIM - 1){ PROCESS_CELL(xb2, yc, zc) }
                    }
                }
            }
            if (__any(cnt > 0)) flush_sk(arr, cnt, bufw, lane, threshS);
            __syncthreads();                       // all publishes visible
            th = dec_f(*(volatile unsigned*)(threshS + lane));
            const float sh = (float)s * HCELL;
            // d20^2 = pn2 - 2*t20 (conservative: th <= true merged t20)
            if (__syncthreads_and(fmaf(-2.f, th, pn2) <= sh * sh)) break;
        }
    }

    __syncthreads();   // all buffer use done before aliased list writes
    float* ml = shmem;

    // Tree merge: (0<-1)(2<-3)(4<-5)(6<-7) -> (0<-2)(4<-6) -> (0<-4)
    if (wave & 1) {
        float* d = ml + (wave >> 1) * (64 * LSTR) + lane * LSTR;
#pragma unroll
        for (int k = 0; k < KNN; ++k) d[k] = arr[k];
    }
    __syncthreads();
    if (!(wave & 1)) {
        const float* sL = ml + (wave >> 1) * (64 * LSTR) + lane * LSTR;
#pragma unroll
        for (int k = 0; k < KNN; ++k) insert_t(arr, sL[k]);
    }
    __syncthreads();
    if (!(wave & 1) && (wave & 2)) {
        float* d = ml + (wave >> 2) * (64 * LSTR) + lane * LSTR;
#pragma unroll
        for (int k = 0; k < KNN; ++k) d[k] = arr[k];
    }
    __syncthreads();
    if ((wave & 3) == 0) {
        const float* sL = ml + (wave >> 2) * (64 * LSTR) + lane * LSTR;
#pragma unroll
        for (int k = 0; k < KNN; ++k) insert_t(arr, sL[k]);
    }
    __syncthreads();
    if (wave == 4) {
        float* d = ml + lane * LSTR;
#pragma unroll
        for (int k = 0; k < KNN; ++k) d[k] = arr[k];
    }
    __syncthreads();
    if (wave == 0) {
        const float* sL = ml + lane * LSTR;
#pragma unroll
        for (int k = 0; k < KNN; ++k) insert_t(arr, sL[k]);
        const int orow = perm[base + lane];
        finalize_row(arr, px, py, pz, orow, lane, kmaxA, kminA, acc);
    }
}

// ---- fallbacks (verified in earlier rounds) ----

__global__ __launch_bounds__(256) void prep_kernel(
    const float* __restrict__ x, float4* __restrict__ tile4, float* __restrict__ acc)
{
    const int i = blockIdx.x * 256 + threadIdx.x;
    const int b = i >> 13;
    const int m = i & (NPTS - 1);
    const float* xb = x + b * 3 * NPTS;
    const float qx = xb[m], qy = xb[NPTS + m], qz = xb[2 * NPTS + m];
    tile4[i] = make_float4(qx, qy, qz, -0.5f * (qx * qx + qy * qy + qz * qz));
    if (i < 2) acc[i] = 0.f;
}

__device__ __forceinline__ void flush_buf(float arr[KNN], int& cnt,
    const float* bufw, int lane, unsigned* threshS) {
#pragma unroll
    for (int s = 0; s < CAP; ++s) {
        const float v = bufw[s * 64 + lane];
        insert_t(arr, (s < cnt) ? v : NEG_INF);
    }
    cnt = 0;
    atomicMax(&threshS[lane], enc_f(arr[KNN - 1]));
}

__global__ __launch_bounds__(BLK, 8) void knn_kernel(
    const float* __restrict__ x, const float4* __restrict__ tile4,
    float* __restrict__ kmaxA, float* __restrict__ kminA, float* __restrict__ acc)
{
    __shared__ float shmem[(WPB - 1) * 64 * LSTR];
    __shared__ unsigned threshS[64];

    const int tid  = threadIdx.x;
    const int lane = tid & 63;
    const int wave = __builtin_amdgcn_readfirstlane(tid >> 6);
    const int rowBase = blockIdx.x * 64;
    const int row  = rowBase + lane;
    const int b    = rowBase >> 13;
    const int n    = row & (NPTS - 1);
    const float* xb = x + b * 3 * NPTS;

    const float px = xb[n];
    const float py = xb[NPTS + n];
    const float pz = xb[2 * NPTS + n];

    if (tid < 64) threshS[tid] = enc_f(NEG_INF);

    float arr[KNN];
#pragma unroll
    for (int j = 0; j < KNN; ++j) arr[j] = NEG_INF;

    float* bufw = shmem + wave * (CAP * 64);
    int cnt = 0;
    __syncthreads();

    const float4* __restrict__ tp = tile4 + b * NPTS + wave * SLICE;
    float th = NEG_INF;
    for (int c = 0; c < SLICE / 32; ++c) {
        th = dec_f(*(volatile unsigned*)(threshS + lane));
        const float4* tq = tp + c * 32;
        for (int g = 0; g < 8; ++g) {
#pragma unroll
            for (int u = 0; u < 4; ++u) {
                const float4 q = tq[g * 4 + u];
                const float t = fmaf(q.x, px, fmaf(q.y, py, fmaf(q.z, pz, q.w)));
                if (t > th) { bufw[cnt * 64 + lane] = t; ++cnt; }
            }
            if (__any(cnt > CAP - 4)) {
                flush_buf(arr, cnt, bufw, lane, threshS);
                th = dec_f(*(volatile unsigned*)(threshS + lane));
            }
        }
    }
    if (__any(cnt > 0)) flush_buf(arr, cnt, bufw, lane, threshS);
    __syncthreads();

    if (wave > 0) {
        float* dst = shmem + ((wave - 1) * 64 + lane) * LSTR;
#pragma unroll
        for (int j = 0; j < KNN; ++j) dst[j] = arr[j];
    }
    __syncthreads();

    if (wave == 0) {
        for (int wsrc = 0; wsrc < WPB - 1; ++wsrc) {
            const float* src = shmem + (wsrc * 64 + lane) * LSTR;
#pragma unroll
            for (int k = 0; k < KNN; ++k) insert_t(arr, src[k]);
        }
        finalize_row(arr, px, py, pz, row, lane, kmaxA, kminA, acc);
    }
}

__global__ __launch_bounds__(BLK) void knn_kernel_lds(
    const float* __restrict__ x,
    float* __restrict__ kmaxA, float* __restrict__ kminA, float* __restrict__ acc)
{
    __shared__ float4 tile[2048];
    __shared__ float  lists[(WPB - 1) * 64 * LSTR];

    const int tid  = threadIdx.x;
    const int lane = tid & 63;
    const int wave = tid >> 6;
    const int rowBase = blockIdx.x * 64;
    const int row  = rowBase + lane;
    const int b    = rowBase >> 13;
    const int n    = row & (NPTS - 1);
    const float* xb = x + b * 3 * NPTS;

    const float px = xb[n];
    const float py = xb[NPTS + n];
    const float pz = xb[2 * NPTS + n];

    float arr[KNN];
#pragma unroll
    for (int j = 0; j < KNN; ++j) arr[j] = NEG_INF;

    for (int t0 = 0; t0 < NPTS; t0 += 2048) {
        __syncthreads();
        const int i4 = tid * 4;
        const float4 qx4 = *(const float4*)(xb + t0 + i4);
        const float4 qy4 = *(const float4*)(xb + NPTS + t0 + i4);
        const float4 qz4 = *(const float4*)(xb + 2 * NPTS + t0 + i4);
        tile[i4 + 0] = make_float4(qx4.x, qy4.x, qz4.x, -0.5f * (qx4.x*qx4.x + qy4.x*qy4.x + qz4.x*qz4.x));
        tile[i4 + 1] = make_float4(qx4.y, qy4.y, qz4.y, -0.5f * (qx4.y*qx4.y + qy4.y*qy4.y + qz4.y*qz4.y));
        tile[i4 + 2] = make_float4(qx4.z, qy4.z, qz4.z, -0.5f * (qx4.z*qx4.z + qy4.z*qy4.z + qz4.z*qz4.z));
        tile[i4 + 3] = make_float4(qx4.w, qy4.w, qz4.w, -0.5f * (qx4.w*qx4.w + qy4.w*qy4.w + qz4.w*qz4.w));
        __syncthreads();
        const float4* basep = tile + wave * 256;
#pragma unroll 4
        for (int i = 0; i < 256; ++i) {
            const float4 q = basep[i];
            float t = fmaf(q.x, px, fmaf(q.y, py, fmaf(q.z, pz, q.w)));
            insert_t(arr, t);
        }
    }
    __syncthreads();

    if (wave > 0) {
        float* dst = lists + ((wave - 1) * 64 + lane) * LSTR;
#pragma unroll
        for (int j = 0; j < KNN; ++j) dst[j] = arr[j];
    }
    __syncthreads();

    if (wave == 0) {
        for (int wsrc = 0; wsrc < WPB - 1; ++wsrc) {
            const float* src = lists + (wsrc * 64 + lane) * LSTR;
#pragma unroll
            for (int k = 0; k < KNN; ++k) insert_t(arr, src[k]);
        }
        finalize_row(arr, px, py, pz, row, lane, kmaxA, kminA, acc);
    }
}

// K2: per-thread BN-coefficient computation + output.
__global__ __launch_bounds__(256) void out_kernel(
    const float* __restrict__ kmaxA, const float* __restrict__ kminA,
    const float* __restrict__ acc,
    const float* __restrict__ w, const float* __restrict__ gamma,
    const float* __restrict__ beta, float* __restrict__ out)
{
    const int r = blockIdx.x * 256 + threadIdx.x;
    const int b = r >> 13;
    const int n = r & (NPTS - 1);
    const float mu  = acc[0] * (1.0f / MTOTF);
    float var = acc[1] * (1.0f / MTOTF) - mu * mu;
    var = fmaxf(var, 0.f);
    const float kmax = kmaxA[r];
    const float kmin = kminA[r];
#pragma unroll
    for (int c = 0; c < 16; ++c) {
        const float wc = w[c];
        const float a = gamma[c] * wc * rsqrtf(wc * wc * var + 1e-5f);
        const float d = beta[c] - a * mu;
        float v = a * (a >= 0.f ? kmax : kmin) + d;
        v = (v >= 0.f) ? v : 0.2f * v;
        out[(b * 16 + c) * NPTS + n] = v;
    }
}

extern "C" void kernel_launch(void* const* d_in, const int* in_sizes, int n_in,
                              void* d_out, int out_size, void* d_ws, size_t ws_size,
                              hipStream_t stream)
{
    const float* x     = (const float*)d_in[0];
    const float* w     = (const float*)d_in[1];
    const float* gamma = (const float*)d_in[3];
    const float* beta  = (const float*)d_in[4];
    float* out = (float*)d_out;
    float* ws  = (float*)d_ws;

    float* kmaxA = ws;                                // NROWS
    float* kminA = ws + NROWS;                        // NROWS
    float* acc   = ws + 2 * NROWS;                    // 2 (+2 pad)
    float4* sorted4 = (float4*)(ws + 2 * NROWS + 4);  // NROWS float4 (16B aligned)
    int* perm      = (int*)(ws + 2 * NROWS + 4 + 4 * NROWS);
    int* cellid    = perm + NROWS;
    int* cellStart = cellid + NROWS;                  // NB*(BINS+1)
    int* cursor    = cellStart + NB * (BINS + 1);     // NB*BINS

    const size_t need_grid = ((size_t)(2 * NROWS + 4) + 4 * NROWS + NROWS + NROWS
                              + NB * (BINS + 1) + NB * BINS) * 4;
    const size_t need_tile = (size_t)(2 * NROWS + 4) * 4 + (size_t)NROWS * 16;

    if (ws_size >= need_grid) {
        hipMemsetAsync(cursor, 0, (size_t)NB * BINS * 4, stream);
        cell_kernel<<<NROWS / 256, 256, 0, stream>>>(x, cellid, cursor, acc);
        scan_kernel<<<NB, 1024, 0, stream>>>(cursor, cellStart);
        scatter_kernel<<<NROWS / 256, 256, 0, stream>>>(x, cellid, cursor, sorted4, perm);
        knn_grid_kernel<<<NROWS / 64, BLK, 0, stream>>>(sorted4, perm, cellStart,
                                                        kmaxA, kminA, acc);
    } else if (ws_size >= need_tile) {
        float4* tile4 = sorted4;
        prep_kernel<<<NROWS / 256, 256, 0, stream>>>(x, tile4, acc);
        knn_kernel<<<NROWS / 64, BLK, 0, stream>>>(x, tile4, kmaxA, kminA, acc);
    } else {
        prep_kernel<<<1, 256, 0, stream>>>(x, sorted4, acc);    // only zeroes acc
        knn_kernel_lds<<<NROWS / 64, BLK, 0, stream>>>(x, kmaxA, kminA, acc);
    }
    out_kernel<<<NROWS / 256, 256, 0, stream>>>(kmaxA, kminA, acc, w, gamma, beta, out);
}

// Round 6
// 507.115 us; speedup vs baseline: 4.3262x; 4.3262x over previous
//
#include <hip/hip_runtime.h>
#include <hip/hip_cooperative_groups.h>
#include <stdint.h>

namespace cg = cooperative_groups;

#define NPTS  8192
#define NB    4
#define KNN   20
#define NROWS (NB * NPTS)        // 32768
#define MTOTF 655360.0f          // NROWS * KNN
#define WPB   8                  // waves per block; all waves share the same 64 rows
#define BLK   (WPB * 64)         // 512 threads
#define SLICE (NPTS / WPB)       // 1024 candidates per wave (round-1 fallback)
#define HALF  (NPTS / 2)         // 4096 candidates per split block
#define SLICE2 (HALF / WPB)      // 512 candidates per wave
#define LSTR  (KNN + 1)          // padded merge-list stride
#define CAP   12                 // round-1 fallback push-buffer slots
#define CAP2  16                 // split/mega push-buffer slots
#define NGRID (2 * (NROWS / 64)) // 1024 blocks = 4/CU exactly
#define NEG_INF -3.0e38f

__device__ __forceinline__ float med3f(float a, float b, float c) {
    return __builtin_amdgcn_fmed3f(a, b, c);
}

// Monotone float<->uint encoding so LDS atomicMax works as float-max (any sign).
__device__ __forceinline__ unsigned enc_f(float f) {
    unsigned u = __float_as_uint(f);
    return (u & 0x80000000u) ? ~u : (u | 0x80000000u);
}
__device__ __forceinline__ float dec_f(unsigned u) {
    return __uint_as_float((u & 0x80000000u) ? (u & 0x7fffffffu) : ~u);
}

// Insert t into descending top-KNN list (arr[0] = largest t = nearest point).
// Dropping off the bottom is always exact: 20 larger witnesses exist.
__device__ __forceinline__ void insert_t(float arr[KNN], float t) {
#pragma unroll
    for (int j = KNN - 1; j > 0; --j) arr[j] = med3f(t, arr[j - 1], arr[j]);
    arr[0] = fmaxf(arr[0], t);
}

// ---- round-1 fallback flush: fixed CAP, padded ----
__device__ __forceinline__ void flush_buf(float arr[KNN], int& cnt,
    const float* bufw, int lane, unsigned* threshS) {
#pragma unroll
    for (int s = 0; s < CAP; ++s) {
        const float v = bufw[s * 64 + lane];
        insert_t(arr, (s < cnt) ? v : NEG_INF);
    }
    cnt = 0;
    atomicMax(&threshS[lane], enc_f(arr[KNN - 1]));
}

// ---- chunk-skippable flush (4 slots per uniform test), verified in R2 ----
__device__ __forceinline__ void flush_dyn(float arr[KNN], int& cnt,
    const float* bufw, int lane, unsigned* threshS) {
#pragma unroll
    for (int s0 = 0; s0 < CAP2; s0 += 4) {
        if (__any(cnt > s0)) {
#pragma unroll
            for (int s = s0; s < s0 + 4; ++s) {
                const float v = bufw[s * 64 + lane];
                insert_t(arr, (s < cnt) ? v : NEG_INF);
            }
        }
    }
    cnt = 0;
    atomicMax(&threshS[lane], enc_f(arr[KNN - 1]));
}

// Shared tail: caller holds merged descending-t list for output row `row`.
// t = p.q - |q|^2/2, d2 = |p|^2 - 2t  (arr[0] = largest t = nearest).
__device__ __forceinline__ void finalize_row(
    float arr[KNN], float px, float py, float pz, int row, int lane,
    float* __restrict__ kmaxA, float* __restrict__ kminA, float* __restrict__ acc)
{
    const float pn2 = px * px + py * py + pz * pz;
    float sum = 0.f, sum2 = 0.f, dmin = 0.f, dmax = 0.f;
#pragma unroll
    for (int k = 0; k < KNN; ++k) {
        float d2 = fmaxf(fmaf(-2.f, arr[k], pn2), 0.f);
        float d = sqrtf(d2);
        sum += d; sum2 += d2;
        if (k == 0) dmin = d;
        dmax = d;
    }
    kmaxA[row] = dmax;
    kminA[row] = dmin;
#pragma unroll
    for (int o = 32; o; o >>= 1) {
        sum  += __shfl_down(sum,  o, 64);
        sum2 += __shfl_down(sum2, o, 64);
    }
    if (lane == 0) { atomicAdd(acc, sum); atomicAdd(acc + 1, sum2); }
}

// ===================== MEGA (single cooperative dispatch) =====================
// P0 prep -> sync -> P1 R2-verified scan + tree-merge tail -> sync ->
// P2 half-merge + finalize -> sync -> P3 output (1 elem/thread).
// LDS: shmem sized to the CAP2 push buffers (32768B) so 4 blocks/CU is certain;
// tree-merge lists (4*64*21*4 = 21504B) alias it after the drain barrier.
__global__ __launch_bounds__(BLK, 8) void mega_kernel(
    const float* __restrict__ x, const float* __restrict__ w,
    const float* __restrict__ gamma, const float* __restrict__ beta,
    float4* __restrict__ tile4, float* __restrict__ part,
    float* __restrict__ kmaxA, float* __restrict__ kminA,
    float* __restrict__ acc, float* __restrict__ out)
{
    cg::grid_group grid = cg::this_grid();
    __shared__ float shmem[WPB * CAP2 * 64];   // 32768 B
    __shared__ unsigned threshS[64];

    const int tid  = threadIdx.x;
    const int lane = tid & 63;
    const int wave = __builtin_amdgcn_readfirstlane(tid >> 6);
    const int blk  = blockIdx.x;

    // ---- P0: prep tile4[i] = (qx,qy,qz,-|q|^2/2); zero acc (blocks 0..63) ----
    if (blk < NROWS / BLK) {
        const int i = blk * BLK + tid;           // 0..32767
        const int b = i >> 13;
        const int m = i & (NPTS - 1);
        const float* xb = x + b * 3 * NPTS;
        const float qx = xb[m], qy = xb[NPTS + m], qz = xb[2 * NPTS + m];
        tile4[i] = make_float4(qx, qy, qz, -0.5f * (qx * qx + qy * qy + qz * qz));
        if (i < 2) acc[i] = 0.f;
    }
    grid.sync();

    // ---- P1: kNN half-scan (verified R2 machinery) ----
    {
        const int rb   = blk >> 1;               // row-group 0..511
        const int half = blk & 1;                // candidate half
        const int rowBase = rb * 64;
        const int row  = rowBase + lane;
        const int b    = rowBase >> 13;
        const int n    = row & (NPTS - 1);
        const float* xb = x + b * 3 * NPTS;
        const float px = xb[n];
        const float py = xb[NPTS + n];
        const float pz = xb[2 * NPTS + n];

        if (tid < 64) threshS[tid] = enc_f(NEG_INF);

        float arr[KNN];
#pragma unroll
        for (int j = 0; j < KNN; ++j) arr[j] = NEG_INF;
        float* bufw = shmem + wave * (CAP2 * 64);
        __syncthreads();

        const float4* __restrict__ tp = tile4 + b * NPTS + half * HALF + wave * SLICE2;

        // Warm-up: private ladder over first 32; publish real 20-of-32.
#pragma unroll 8
        for (int i = 0; i < 32; ++i) {
            const float4 q = tp[i];
            insert_t(arr, fmaf(q.x, px, fmaf(q.y, py, fmaf(q.z, pz, q.w))));
        }
        atomicMax(&threshS[lane], enc_f(arr[KNN - 1]));

        int cnt = 0;
        for (int c = 1; c < SLICE2 / 32; ++c) {
            float th = dec_f(*(volatile unsigned*)(threshS + lane));
            const float4* tq = tp + c * 32;
            for (int g = 0; g < 8; ++g) {
#pragma unroll
                for (int u = 0; u < 4; ++u) {
                    const float4 q = tq[g * 4 + u];      // wave-uniform -> scalar load
                    const float t = fmaf(q.x, px, fmaf(q.y, py, fmaf(q.z, pz, q.w)));
                    bufw[cnt * 64 + lane] = t;           // always-store (no branch)
                    cnt += (t > th);
                }
                if (__any(cnt > CAP2 - 4)) {
                    flush_dyn(arr, cnt, bufw, lane, threshS);
                    th = dec_f(*(volatile unsigned*)(threshS + lane));
                }
            }
        }
        if (__any(cnt > 0)) flush_dyn(arr, cnt, bufw, lane, threshS);
        __syncthreads();   // all push-buffer use done before aliased list writes

        // Tree merge (verified R4): (0<-1)(2<-3)(4<-5)(6<-7) -> (0<-2)(4<-6) -> (0<-4)
        float* ml = shmem;
        if (wave & 1) {
            float* d = ml + (wave >> 1) * (64 * LSTR) + lane * LSTR;
#pragma unroll
            for (int k = 0; k < KNN; ++k) d[k] = arr[k];
        }
        __syncthreads();
        if (!(wave & 1)) {
            const float* s = ml + (wave >> 1) * (64 * LSTR) + lane * LSTR;
#pragma unroll
            for (int k = 0; k < KNN; ++k) insert_t(arr, s[k]);
        }
        __syncthreads();
        if (!(wave & 1) && (wave & 2)) {
            float* d = ml + (wave >> 2) * (64 * LSTR) + lane * LSTR;
#pragma unroll
            for (int k = 0; k < KNN; ++k) d[k] = arr[k];
        }
        __syncthreads();
        if ((wave & 3) == 0) {
            const float* s = ml + (wave >> 2) * (64 * LSTR) + lane * LSTR;
#pragma unroll
            for (int k = 0; k < KNN; ++k) insert_t(arr, s[k]);
        }
        __syncthreads();
        if (wave == 4) {
            float* d = ml + lane * LSTR;
#pragma unroll
            for (int k = 0; k < KNN; ++k) d[k] = arr[k];
        }
        __syncthreads();
        if (wave == 0) {
            const float* s = ml + lane * LSTR;
#pragma unroll
            for (int k = 0; k < KNN; ++k) insert_t(arr, s[k]);
            float4* dst = (float4*)(part + (row * 2 + half) * KNN);
#pragma unroll
            for (int k = 0; k < KNN; k += 4)
                dst[k >> 2] = make_float4(arr[k], arr[k + 1], arr[k + 2], arr[k + 3]);
        }
    }
    grid.sync();

    // ---- P2: merge the two halves per row + finalize (blocks 0..63) ----
    if (blk < NROWS / BLK) {
        const int r = blk * BLK + tid;           // 0..32767
        const int b = r >> 13;
        const int n = r & (NPTS - 1);
        const float* xb = x + b * 3 * NPTS;
        const float px = xb[n];
        const float py = xb[NPTS + n];
        const float pz = xb[2 * NPTS + n];

        const float4* pA = (const float4*)(part + r * 2 * KNN);
        float arr[KNN];
#pragma unroll
        for (int k = 0; k < KNN; k += 4) {
            const float4 v = pA[k >> 2];
            arr[k] = v.x; arr[k + 1] = v.y; arr[k + 2] = v.z; arr[k + 3] = v.w;
        }
#pragma unroll
        for (int k = 0; k < KNN; k += 4) {
            const float4 v = pA[(KNN + k) >> 2];
            insert_t(arr, v.x); insert_t(arr, v.y); insert_t(arr, v.z); insert_t(arr, v.w);
        }
        finalize_row(arr, px, py, pz, r, lane, kmaxA, kminA, acc);
    }
    grid.sync();

    // ---- P3: output, exactly one element per thread ----
    {
        const int T = blk * BLK + tid;           // 0..524287 = (b*16+c)*NPTS+n
        const int n  = T & (NPTS - 1);
        const int bc = T >> 13;                  // b*16+c (uniform per block)
        const int c  = bc & 15;
        const int b  = bc >> 4;
        const float mu  = acc[0] * (1.0f / MTOTF);
        float var = acc[1] * (1.0f / MTOTF) - mu * mu;
        var = fmaxf(var, 0.f);
        const float wc = w[c];
        const float a  = gamma[c] * wc * rsqrtf(wc * wc * var + 1e-5f);
        const float d  = beta[c] - a * mu;       // conv bias cancels inside BN
        const float km = (a >= 0.f) ? kmaxA[b * NPTS + n] : kminA[b * NPTS + n];
        float v = a * km + d;
        v = (v >= 0.f) ? v : 0.2f * v;
        out[T] = v;
    }
}

// ===================== fallback path (verified R2, 4 dispatches) ==============

__global__ __launch_bounds__(256) void prep_kernel(
    const float* __restrict__ x, float4* __restrict__ tile4, float* __restrict__ acc)
{
    const int i = blockIdx.x * 256 + threadIdx.x;
    const int b = i >> 13;
    const int m = i & (NPTS - 1);
    const float* xb = x + b * 3 * NPTS;
    const float qx = xb[m], qy = xb[NPTS + m], qz = xb[2 * NPTS + m];
    tile4[i] = make_float4(qx, qy, qz, -0.5f * (qx * qx + qy * qy + qz * qz));
    if (i < 2) acc[i] = 0.f;
}

__global__ __launch_bounds__(BLK, 8) void knn_split_kernel(
    const float* __restrict__ x, const float4* __restrict__ tile4,
    float* __restrict__ part)
{
    __shared__ float shmem[(WPB - 1) * 64 * LSTR];
    __shared__ unsigned threshS[64];

    const int tid  = threadIdx.x;
    const int lane = tid & 63;
    const int wave = __builtin_amdgcn_readfirstlane(tid >> 6);
    const int rb   = blockIdx.x >> 1;
    const int half = blockIdx.x & 1;
    const int rowBase = rb * 64;
    const int row  = rowBase + lane;
    const int b    = rowBase >> 13;
    const int n    = row & (NPTS - 1);
    const float* xb = x + b * 3 * NPTS;
    const float px = xb[n];
    const float py = xb[NPTS + n];
    const float pz = xb[2 * NPTS + n];

    if (tid < 64) threshS[tid] = enc_f(NEG_INF);

    float arr[KNN];
#pragma unroll
    for (int j = 0; j < KNN; ++j) arr[j] = NEG_INF;
    float* bufw = shmem + wave * (CAP2 * 64);
    __syncthreads();

    const float4* __restrict__ tp = tile4 + b * NPTS + half * HALF + wave * SLICE2;
#pragma unroll 8
    for (int i = 0; i < 32; ++i) {
        const float4 q = tp[i];
        insert_t(arr, fmaf(q.x, px, fmaf(q.y, py, fmaf(q.z, pz, q.w))));
    }
    atomicMax(&threshS[lane], enc_f(arr[KNN - 1]));

    int cnt = 0;
    for (int c = 1; c < SLICE2 / 32; ++c) {
        float th = dec_f(*(volatile unsigned*)(threshS + lane));
        const float4* tq = tp + c * 32;
        for (int g = 0; g < 8; ++g) {
#pragma unroll
            for (int u = 0; u < 4; ++u) {
                const float4 q = tq[g * 4 + u];
                const float t = fmaf(q.x, px, fmaf(q.y, py, fmaf(q.z, pz, q.w)));
                bufw[cnt * 64 + lane] = t;
                cnt += (t > th);
            }
            if (__any(cnt > CAP2 - 4)) {
                flush_dyn(arr, cnt, bufw, lane, threshS);
                th = dec_f(*(volatile unsigned*)(threshS + lane));
            }
        }
    }
    if (__any(cnt > 0)) flush_dyn(arr, cnt, bufw, lane, threshS);
    __syncthreads();

    if (wave > 0) {
        float* dst = shmem + ((wave - 1) * 64 + lane) * LSTR;
#pragma unroll
        for (int j = 0; j < KNN; ++j) dst[j] = arr[j];
    }
    __syncthreads();

    if (wave == 0) {
        for (int wsrc = 0; wsrc < WPB - 1; ++wsrc) {
            const float* src = shmem + (wsrc * 64 + lane) * LSTR;
#pragma unroll
            for (int k = 0; k < KNN; ++k) insert_t(arr, src[k]);
        }
        float4* dst = (float4*)(part + (row * 2 + half) * KNN);
#pragma unroll
        for (int k = 0; k < KNN; k += 4)
            dst[k >> 2] = make_float4(arr[k], arr[k + 1], arr[k + 2], arr[k + 3]);
    }
}

__global__ __launch_bounds__(256) void merge_kernel(
    const float* __restrict__ x, const float* __restrict__ part,
    float* __restrict__ kmaxA, float* __restrict__ kminA, float* __restrict__ acc)
{
    const int r = blockIdx.x * 256 + threadIdx.x;
    const int lane = threadIdx.x & 63;
    const int b = r >> 13;
    const int n = r & (NPTS - 1);
    const float* xb = x + b * 3 * NPTS;
    const float px = xb[n];
    const float py = xb[NPTS + n];
    const float pz = xb[2 * NPTS + n];

    const float4* pA = (const float4*)(part + r * 2 * KNN);
    float arr[KNN];
#pragma unroll
    for (int k = 0; k < KNN; k += 4) {
        const float4 v = pA[k >> 2];
        arr[k] = v.x; arr[k + 1] = v.y; arr[k + 2] = v.z; arr[k + 3] = v.w;
    }
#pragma unroll
    for (int k = 0; k < KNN; k += 4) {
        const float4 v = pA[(KNN + k) >> 2];
        insert_t(arr, v.x); insert_t(arr, v.y); insert_t(arr, v.z); insert_t(arr, v.w);
    }
    finalize_row(arr, px, py, pz, r, lane, kmaxA, kminA, acc);
}

__global__ __launch_bounds__(BLK, 8) void knn_kernel(
    const float* __restrict__ x, const float4* __restrict__ tile4,
    float* __restrict__ kmaxA, float* __restrict__ kminA, float* __restrict__ acc)
{
    __shared__ float shmem[(WPB - 1) * 64 * LSTR];
    __shared__ unsigned threshS[64];

    const int tid  = threadIdx.x;
    const int lane = tid & 63;
    const int wave = __builtin_amdgcn_readfirstlane(tid >> 6);
    const int rowBase = blockIdx.x * 64;
    const int row  = rowBase + lane;
    const int b    = rowBase >> 13;
    const int n    = row & (NPTS - 1);
    const float* xb = x + b * 3 * NPTS;
    const float px = xb[n];
    const float py = xb[NPTS + n];
    const float pz = xb[2 * NPTS + n];

    if (tid < 64) threshS[tid] = enc_f(NEG_INF);

    float arr[KNN];
#pragma unroll
    for (int j = 0; j < KNN; ++j) arr[j] = NEG_INF;
    float* bufw = shmem + wave * (CAP * 64);
    int cnt = 0;
    __syncthreads();

    const float4* __restrict__ tp = tile4 + b * NPTS + wave * SLICE;
    float th = NEG_INF;
    for (int c = 0; c < SLICE / 32; ++c) {
        th = dec_f(*(volatile unsigned*)(threshS + lane));
        const float4* tq = tp + c * 32;
        for (int g = 0; g < 8; ++g) {
#pragma unroll
            for (int u = 0; u < 4; ++u) {
                const float4 q = tq[g * 4 + u];
                const float t = fmaf(q.x, px, fmaf(q.y, py, fmaf(q.z, pz, q.w)));
                if (t > th) { bufw[cnt * 64 + lane] = t; ++cnt; }
            }
            if (__any(cnt > CAP - 4)) {
                flush_buf(arr, cnt, bufw, lane, threshS);
                th = dec_f(*(volatile unsigned*)(threshS + lane));
            }
        }
    }
    if (__any(cnt > 0)) flush_buf(arr, cnt, bufw, lane, threshS);
    __syncthreads();

    if (wave > 0) {
        float* dst = shmem + ((wave - 1) * 64 + lane) * LSTR;
#pragma unroll
        for (int j = 0; j < KNN; ++j) dst[j] = arr[j];
    }
    __syncthreads();

    if (wave == 0) {
        for (int wsrc = 0; wsrc < WPB - 1; ++wsrc) {
            const float* src = shmem + (wsrc * 64 + lane) * LSTR;
#pragma unroll
            for (int k = 0; k < KNN; ++k) insert_t(arr, src[k]);
        }
        finalize_row(arr, px, py, pz, row, lane, kmaxA, kminA, acc);
    }
}

__global__ __launch_bounds__(BLK) void knn_kernel_lds(
    const float* __restrict__ x,
    float* __restrict__ kmaxA, float* __restrict__ kminA, float* __restrict__ acc)
{
    __shared__ float4 tile[2048];
    __shared__ float  lists[(WPB - 1) * 64 * LSTR];

    const int tid  = threadIdx.x;
    const int lane = tid & 63;
    const int wave = tid >> 6;
    const int rowBase = blockIdx.x * 64;
    const int row  = rowBase + lane;
    const int b    = rowBase >> 13;
    const int n    = row & (NPTS - 1);
    const float* xb = x + b * 3 * NPTS;
    const float px = xb[n];
    const float py = xb[NPTS + n];
    const float pz = xb[2 * NPTS + n];

    float arr[KNN];
#pragma unroll
    for (int j = 0; j < KNN; ++j) arr[j] = NEG_INF;

    for (int t0 = 0; t0 < NPTS; t0 += 2048) {
        __syncthreads();
        const int i4 = tid * 4;
        const float4 qx4 = *(const float4*)(xb + t0 + i4);
        const float4 qy4 = *(const float4*)(xb + NPTS + t0 + i4);
        const float4 qz4 = *(const float4*)(xb + 2 * NPTS + t0 + i4);
        tile[i4 + 0] = make_float4(qx4.x, qy4.x, qz4.x, -0.5f * (qx4.x*qx4.x + qy4.x*qy4.x + qz4.x*qz4.x));
        tile[i4 + 1] = make_float4(qx4.y, qy4.y, qz4.y, -0.5f * (qx4.y*qx4.y + qy4.y*qy4.y + qz4.y*qz4.y));
        tile[i4 + 2] = make_float4(qx4.z, qy4.z, qz4.z, -0.5f * (qx4.z*qx4.z + qy4.z*qy4.z + qz4.z*qz4.z));
        tile[i4 + 3] = make_float4(qx4.w, qy4.w, qz4.w, -0.5f * (qx4.w*qx4.w + qy4.w*qy4.w + qz4.w*qz4.w));
        __syncthreads();
        const float4* basep = tile + wave * 256;
#pragma unroll 4
        for (int i = 0; i < 256; ++i) {
            const float4 q = basep[i];
            float t = fmaf(q.x, px, fmaf(q.y, py, fmaf(q.z, pz, q.w)));
            insert_t(arr, t);
        }
    }
    __syncthreads();

    if (wave > 0) {
        float* dst = lists + ((wave - 1) * 64 + lane) * LSTR;
#pragma unroll
        for (int j = 0; j < KNN; ++j) dst[j] = arr[j];
    }
    __syncthreads();

    if (wave == 0) {
        for (int wsrc = 0; wsrc < WPB - 1; ++wsrc) {
            const float* src = lists + (wsrc * 64 + lane) * LSTR;
#pragma unroll
            for (int k = 0; k < KNN; ++k) insert_t(arr, src[k]);
        }
        finalize_row(arr, px, py, pz, row, lane, kmaxA, kminA, acc);
    }
}

__global__ __launch_bounds__(256) void out_kernel(
    const float* __restrict__ kmaxA, const float* __restrict__ kminA,
    const float* __restrict__ acc,
    const float* __restrict__ w, const float* __restrict__ gamma,
    const float* __restrict__ beta, float* __restrict__ out)
{
    const int r = blockIdx.x * 256 + threadIdx.x;
    const int b = r >> 13;
    const int n = r & (NPTS - 1);
    const float mu  = acc[0] * (1.0f / MTOTF);
    float var = acc[1] * (1.0f / MTOTF) - mu * mu;
    var = fmaxf(var, 0.f);
    const float kmax = kmaxA[r];
    const float kmin = kminA[r];
#pragma unroll
    for (int c = 0; c < 16; ++c) {
        const float wc = w[c];
        const float a = gamma[c] * wc * rsqrtf(wc * wc * var + 1e-5f);
        const float d = beta[c] - a * mu;
        float v = a * (a >= 0.f ? kmax : kmin) + d;
        v = (v >= 0.f) ? v : 0.2f * v;
        out[(b * 16 + c) * NPTS + n] = v;
    }
}

extern "C" void kernel_launch(void* const* d_in, const int* in_sizes, int n_in,
                              void* d_out, int out_size, void* d_ws, size_t ws_size,
                              hipStream_t stream)
{
    const float* x     = (const float*)d_in[0];
    const float* w     = (const float*)d_in[1];
    const float* gamma = (const float*)d_in[3];
    const float* beta  = (const float*)d_in[4];
    float* out = (float*)d_out;
    float* ws  = (float*)d_ws;

    float* kmaxA = ws;                                // NROWS
    float* kminA = ws + NROWS;                        // NROWS
    float* acc   = ws + 2 * NROWS;                    // 2 (+2 pad)
    float4* tile4 = (float4*)(ws + 2 * NROWS + 4);    // NROWS float4, 16B-aligned
    float* part  = ws + (2 * NROWS + 4) + 4 * NROWS;  // NROWS*2*KNN floats
    const size_t need_tile  = (size_t)(2 * NROWS + 4) * 4 + (size_t)NROWS * 16;
    const size_t need_split = need_tile + (size_t)NROWS * 2 * KNN * 4;

    if (ws_size >= need_split) {
        // Primary: single cooperative dispatch (4 blocks/CU exactly: 33KB LDS,
        // <=64 VGPR via launch_bounds, 1024 = 4*256 blocks).
        void* args[] = {(void*)&x, (void*)&w, (void*)&gamma, (void*)&beta,
                        (void*)&tile4, (void*)&part, (void*)&kmaxA, (void*)&kminA,
                        (void*)&acc, (void*)&out};
        hipError_t e = hipLaunchCooperativeKernel(
            reinterpret_cast<void*>(mega_kernel),
            dim3(NGRID), dim3(BLK), args, 0, stream);
        if (e == hipSuccess) return;
        (void)hipGetLastError();                      // clear; fall back to R2 path

        prep_kernel<<<NROWS / 256, 256, 0, stream>>>(x, tile4, acc);
        knn_split_kernel<<<NGRID, BLK, 0, stream>>>(x, tile4, part);
        merge_kernel<<<NROWS / 256, 256, 0, stream>>>(x, part, kmaxA, kminA, acc);
    } else if (ws_size >= need_tile) {
        prep_kernel<<<NROWS / 256, 256, 0, stream>>>(x, tile4, acc);
        knn_kernel<<<NROWS / 64, BLK, 0, stream>>>(x, tile4, kmaxA, kminA, acc);
    } else {
        prep_kernel<<<1, 256, 0, stream>>>(x, tile4, acc);      // only zeroes acc
        knn_kernel_lds<<<NROWS / 64, BLK, 0, stream>>>(x, kmaxA, kminA, acc);
    }
    out_kernel<<<NROWS / 256, 256, 0, stream>>>(kmaxA, kminA, acc, w, gamma, beta, out);
}

// Round 7
// 234.558 us; speedup vs baseline: 9.3533x; 2.1620x over previous
//
#include <hip/hip_runtime.h>
#include <stdint.h>

#define NPTS  8192
#define NB    4
#define KNN   20
#define NROWS (NB * NPTS)        // 32768
#define NGROUPS (NROWS / 64)     // 512 row-groups
#define MTOTF 655360.0f          // NROWS * KNN
#define WPB   8                  // waves per block; all waves share the same 64 rows
#define BLK   (WPB * 64)         // 512 threads
#define SLICE (NPTS / WPB)       // 1024 candidates per wave (round-1 fallback)
#define HALF  (NPTS / 2)         // 4096 candidates per split block
#define SLICE2 (HALF / WPB)      // 512 candidates per wave
#define LSTR  (KNN + 1)          // padded merge-list stride
#define CAP   12                 // round-1 fallback push-buffer slots
#define CAP2  16                 // split push-buffer slots
#define NGRID (2 * NGROUPS)      // 1024 blocks = 4/CU
#define NEG_INF -3.0e38f

__device__ __forceinline__ float med3f(float a, float b, float c) {
    return __builtin_amdgcn_fmed3f(a, b, c);
}

// Monotone float<->uint encoding so LDS atomicMax works as float-max (any sign).
__device__ __forceinline__ unsigned enc_f(float f) {
    unsigned u = __float_as_uint(f);
    return (u & 0x80000000u) ? ~u : (u | 0x80000000u);
}
__device__ __forceinline__ float dec_f(unsigned u) {
    return __uint_as_float((u & 0x80000000u) ? (u & 0x7fffffffu) : ~u);
}

// Insert t into descending top-KNN list (arr[0] = largest t = nearest point).
// Dropping off the bottom is always exact: 20 larger witnesses exist.
__device__ __forceinline__ void insert_t(float arr[KNN], float t) {
#pragma unroll
    for (int j = KNN - 1; j > 0; --j) arr[j] = med3f(t, arr[j - 1], arr[j]);
    arr[0] = fmaxf(arr[0], t);
}

// ---- round-1 fallback flush: fixed CAP, padded ----
__device__ __forceinline__ void flush_buf(float arr[KNN], int& cnt,
    const float* bufw, int lane, unsigned* threshS) {
#pragma unroll
    for (int s = 0; s < CAP; ++s) {
        const float v = bufw[s * 64 + lane];
        insert_t(arr, (s < cnt) ? v : NEG_INF);
    }
    cnt = 0;
    atomicMax(&threshS[lane], enc_f(arr[KNN - 1]));
}

// ---- chunk-skippable flush (4 slots per uniform test), verified in R2 ----
__device__ __forceinline__ void flush_dyn(float arr[KNN], int& cnt,
    const float* bufw, int lane, unsigned* threshS) {
#pragma unroll
    for (int s0 = 0; s0 < CAP2; s0 += 4) {
        if (__any(cnt > s0)) {
#pragma unroll
            for (int s = s0; s < s0 + 4; ++s) {
                const float v = bufw[s * 64 + lane];
                insert_t(arr, (s < cnt) ? v : NEG_INF);
            }
        }
    }
    cnt = 0;
    atomicMax(&threshS[lane], enc_f(arr[KNN - 1]));
}

// Shared tail: caller holds merged descending-t list for output row `row`.
// t = p.q - |q|^2/2, d2 = |p|^2 - 2t  (arr[0] = largest t = nearest).
__device__ __forceinline__ void finalize_row(
    float arr[KNN], float px, float py, float pz, int row, int lane,
    float* __restrict__ kmaxA, float* __restrict__ kminA, float* __restrict__ acc)
{
    const float pn2 = px * px + py * py + pz * pz;
    float sum = 0.f, sum2 = 0.f, dmin = 0.f, dmax = 0.f;
#pragma unroll
    for (int k = 0; k < KNN; ++k) {
        float d2 = fmaxf(fmaf(-2.f, arr[k], pn2), 0.f);
        float d = sqrtf(d2);
        sum += d; sum2 += d2;
        if (k == 0) dmin = d;
        dmax = d;
    }
    kmaxA[row] = dmax;
    kminA[row] = dmin;
#pragma unroll
    for (int o = 32; o; o >>= 1) {
        sum  += __shfl_down(sum,  o, 64);
        sum2 += __shfl_down(sum2, o, 64);
    }
    if (lane == 0) { atomicAdd(acc, sum); atomicAdd(acc + 1, sum2); }
}

// Prep: tile4[i] = (qx,qy,qz,-|q|^2/2); zero acc and the merge tickets.
__global__ __launch_bounds__(256) void prep_kernel(
    const float* __restrict__ x, float4* __restrict__ tile4,
    float* __restrict__ acc, int* __restrict__ ticket)
{
    const int i = blockIdx.x * 256 + threadIdx.x;    // 0..32767
    const int b = i >> 13;
    const int m = i & (NPTS - 1);
    const float* xb = x + b * 3 * NPTS;
    const float qx = xb[m], qy = xb[NPTS + m], qz = xb[2 * NPTS + m];
    tile4[i] = make_float4(qx, qy, qz, -0.5f * (qx * qx + qy * qy + qz * qz));
    if (i < 2) acc[i] = 0.f;
    if (ticket && i < NGROUPS) ticket[i] = 0;
}

// K1 (main): R2-verified half-scan + tree merge, then LAST-BLOCK MERGE:
// both half-blocks of a row-group publish their sorted partial top-20 to
// `part`; the second to arrive (atomic ticket, no waiting -> deadlock-free
// under any scheduling) merges the partner's list and finalizes the rows.
// Eliminates the standalone merge dispatch (~15 us node cost).
__global__ __launch_bounds__(BLK, 8) void knn_fused_kernel(
    const float* __restrict__ x, const float4* __restrict__ tile4,
    float* __restrict__ part, int* __restrict__ ticket,
    float* __restrict__ kmaxA, float* __restrict__ kminA, float* __restrict__ acc)
{
    // 32 KB push buffers; tree-merge lists (4*64*21*4 = 21504 B) alias them.
    __shared__ float shmem[WPB * CAP2 * 64];
    __shared__ unsigned threshS[64];

    const int tid  = threadIdx.x;
    const int lane = tid & 63;
    const int wave = __builtin_amdgcn_readfirstlane(tid >> 6);
    const int rb   = blockIdx.x >> 1;        // row-group 0..511
    const int half = blockIdx.x & 1;         // candidate half
    const int rowBase = rb * 64;
    const int row  = rowBase + lane;
    const int b    = rowBase >> 13;
    const int n    = row & (NPTS - 1);
    const float* xb = x + b * 3 * NPTS;
    const float px = xb[n];
    const float py = xb[NPTS + n];
    const float pz = xb[2 * NPTS + n];

    if (tid < 64) threshS[tid] = enc_f(NEG_INF);

    float arr[KNN];
#pragma unroll
    for (int j = 0; j < KNN; ++j) arr[j] = NEG_INF;
    float* bufw = shmem + wave * (CAP2 * 64);
    __syncthreads();

    const float4* __restrict__ tp = tile4 + b * NPTS + half * HALF + wave * SLICE2;

    // Warm-up: private ladder over first 32; publish real 20-of-32 threshold.
#pragma unroll 8
    for (int i = 0; i < 32; ++i) {
        const float4 q = tp[i];
        insert_t(arr, fmaf(q.x, px, fmaf(q.y, py, fmaf(q.z, pz, q.w))));
    }
    atomicMax(&threshS[lane], enc_f(arr[KNN - 1]));

    int cnt = 0;
    for (int c = 1; c < SLICE2 / 32; ++c) {
        float th = dec_f(*(volatile unsigned*)(threshS + lane));
        const float4* tq = tp + c * 32;
        for (int g = 0; g < 8; ++g) {
#pragma unroll
            for (int u = 0; u < 4; ++u) {
                const float4 q = tq[g * 4 + u];      // wave-uniform -> scalar load
                const float t = fmaf(q.x, px, fmaf(q.y, py, fmaf(q.z, pz, q.w)));
                bufw[cnt * 64 + lane] = t;           // always-store (no branch)
                cnt += (t > th);
            }
            if (__any(cnt > CAP2 - 4)) {
                flush_dyn(arr, cnt, bufw, lane, threshS);
                th = dec_f(*(volatile unsigned*)(threshS + lane));
            }
        }
    }
    if (__any(cnt > 0)) flush_dyn(arr, cnt, bufw, lane, threshS);
    __syncthreads();   // all push-buffer use done before aliased list writes

    // Tree merge (verified R4/R6): (0<-1)(2<-3)(4<-5)(6<-7) -> (0<-2)(4<-6) -> (0<-4)
    float* ml = shmem;
    if (wave & 1) {
        float* d = ml + (wave >> 1) * (64 * LSTR) + lane * LSTR;
#pragma unroll
        for (int k = 0; k < KNN; ++k) d[k] = arr[k];
    }
    __syncthreads();
    if (!(wave & 1)) {
        const float* s = ml + (wave >> 1) * (64 * LSTR) + lane * LSTR;
#pragma unroll
        for (int k = 0; k < KNN; ++k) insert_t(arr, s[k]);
    }
    __syncthreads();
    if (!(wave & 1) && (wave & 2)) {
        float* d = ml + (wave >> 2) * (64 * LSTR) + lane * LSTR;
#pragma unroll
        for (int k = 0; k < KNN; ++k) d[k] = arr[k];
    }
    __syncthreads();
    if ((wave & 3) == 0) {
        const float* s = ml + (wave >> 2) * (64 * LSTR) + lane * LSTR;
#pragma unroll
        for (int k = 0; k < KNN; ++k) insert_t(arr, s[k]);
    }
    __syncthreads();
    if (wave == 4) {
        float* d = ml + lane * LSTR;
#pragma unroll
        for (int k = 0; k < KNN; ++k) d[k] = arr[k];
    }
    __syncthreads();
    if (wave == 0) {
        const float* s = ml + lane * LSTR;
#pragma unroll
        for (int k = 0; k < KNN; ++k) insert_t(arr, s[k]);

        // publish my sorted partial list
        float4* dst = (float4*)(part + (row * 2 + half) * KNN);
#pragma unroll
        for (int k = 0; k < KNN; k += 4)
            dst[k >> 2] = make_float4(arr[k], arr[k + 1], arr[k + 2], arr[k + 3]);

        // last-block merge: no waiting, order-independent, deadlock-free
        __threadfence();                              // release my part writes
        int old = 0;
        if (lane == 0) old = atomicAdd(&ticket[rb], 1);
        old = __shfl(old, 0, 64);
        if (old == 1) {                               // I'm second: partner done
            __threadfence();                          // acquire partner's writes
            const float* srcp = part + (row * 2 + (half ^ 1)) * KNN;
#pragma unroll
            for (int k = 0; k < KNN; ++k) insert_t(arr, srcp[k]);
            finalize_row(arr, px, py, pz, row, lane, kmaxA, kminA, acc);
        }
    }
}

// K2: output, one element per thread (8192 waves -> latency well hidden).
__global__ __launch_bounds__(256) void out_elem_kernel(
    const float* __restrict__ kmaxA, const float* __restrict__ kminA,
    const float* __restrict__ acc,
    const float* __restrict__ w, const float* __restrict__ gamma,
    const float* __restrict__ beta, float* __restrict__ out)
{
    const int T = blockIdx.x * 256 + threadIdx.x;    // 0..524287 = (b*16+c)*NPTS+n
    const int n  = T & (NPTS - 1);
    const int bc = T >> 13;
    const int c  = bc & 15;
    const int b  = bc >> 4;
    const float mu  = acc[0] * (1.0f / MTOTF);
    float var = acc[1] * (1.0f / MTOTF) - mu * mu;
    var = fmaxf(var, 0.f);
    const float wc = w[c];
    const float a  = gamma[c] * wc * rsqrtf(wc * wc * var + 1e-5f);
    const float d  = beta[c] - a * mu;               // conv bias cancels inside BN
    const float km = (a >= 0.f) ? kmaxA[b * NPTS + n] : kminA[b * NPTS + n];
    float v = a * km + d;
    v = (v >= 0.f) ? v : 0.2f * v;
    out[T] = v;
}

// ===================== fallback path (small ws; verified R1 structure) ========

__global__ __launch_bounds__(BLK, 8) void knn_kernel(
    const float* __restrict__ x, const float4* __restrict__ tile4,
    float* __restrict__ kmaxA, float* __restrict__ kminA, float* __restrict__ acc)
{
    __shared__ float shmem[(WPB - 1) * 64 * LSTR];
    __shared__ unsigned threshS[64];

    const int tid  = threadIdx.x;
    const int lane = tid & 63;
    const int wave = __builtin_amdgcn_readfirstlane(tid >> 6);
    const int rowBase = blockIdx.x * 64;
    const int row  = rowBase + lane;
    const int b    = rowBase >> 13;
    const int n    = row & (NPTS - 1);
    const float* xb = x + b * 3 * NPTS;
    const float px = xb[n];
    const float py = xb[NPTS + n];
    const float pz = xb[2 * NPTS + n];

    if (tid < 64) threshS[tid] = enc_f(NEG_INF);

    float arr[KNN];
#pragma unroll
    for (int j = 0; j < KNN; ++j) arr[j] = NEG_INF;
    float* bufw = shmem + wave * (CAP * 64);
    int cnt = 0;
    __syncthreads();

    const float4* __restrict__ tp = tile4 + b * NPTS + wave * SLICE;
    float th = NEG_INF;
    for (int c = 0; c < SLICE / 32; ++c) {
        th = dec_f(*(volatile unsigned*)(threshS + lane));
        const float4* tq = tp + c * 32;
        for (int g = 0; g < 8; ++g) {
#pragma unroll
            for (int u = 0; u < 4; ++u) {
                const float4 q = tq[g * 4 + u];
                const float t = fmaf(q.x, px, fmaf(q.y, py, fmaf(q.z, pz, q.w)));
                if (t > th) { bufw[cnt * 64 + lane] = t; ++cnt; }
            }
            if (__any(cnt > CAP - 4)) {
                flush_buf(arr, cnt, bufw, lane, threshS);
                th = dec_f(*(volatile unsigned*)(threshS + lane));
            }
        }
    }
    if (__any(cnt > 0)) flush_buf(arr, cnt, bufw, lane, threshS);
    __syncthreads();

    if (wave > 0) {
        float* dst = shmem + ((wave - 1) * 64 + lane) * LSTR;
#pragma unroll
        for (int j = 0; j < KNN; ++j) dst[j] = arr[j];
    }
    __syncthreads();

    if (wave == 0) {
        for (int wsrc = 0; wsrc < WPB - 1; ++wsrc) {
            const float* src = shmem + (wsrc * 64 + lane) * LSTR;
#pragma unroll
            for (int k = 0; k < KNN; ++k) insert_t(arr, src[k]);
        }
        finalize_row(arr, px, py, pz, row, lane, kmaxA, kminA, acc);
    }
}

__global__ __launch_bounds__(BLK) void knn_kernel_lds(
    const float* __restrict__ x,
    float* __restrict__ kmaxA, float* __restrict__ kminA, float* __restrict__ acc)
{
    __shared__ float4 tile[2048];
    __shared__ float  lists[(WPB - 1) * 64 * LSTR];

    const int tid  = threadIdx.x;
    const int lane = tid & 63;
    const int wave = tid >> 6;
    const int rowBase = blockIdx.x * 64;
    const int row  = rowBase + lane;
    const int b    = rowBase >> 13;
    const int n    = row & (NPTS - 1);
    const float* xb = x + b * 3 * NPTS;
    const float px = xb[n];
    const float py = xb[NPTS + n];
    const float pz = xb[2 * NPTS + n];

    float arr[KNN];
#pragma unroll
    for (int j = 0; j < KNN; ++j) arr[j] = NEG_INF;

    for (int t0 = 0; t0 < NPTS; t0 += 2048) {
        __syncthreads();
        const int i4 = tid * 4;
        const float4 qx4 = *(const float4*)(xb + t0 + i4);
        const float4 qy4 = *(const float4*)(xb + NPTS + t0 + i4);
        const float4 qz4 = *(const float4*)(xb + 2 * NPTS + t0 + i4);
        tile[i4 + 0] = make_float4(qx4.x, qy4.x, qz4.x, -0.5f * (qx4.x*qx4.x + qy4.x*qy4.x + qz4.x*qz4.x));
        tile[i4 + 1] = make_float4(qx4.y, qy4.y, qz4.y, -0.5f * (qx4.y*qx4.y + qy4.y*qy4.y + qz4.y*qz4.y));
        tile[i4 + 2] = make_float4(qx4.z, qy4.z, qz4.z, -0.5f * (qx4.z*qx4.z + qy4.z*qy4.z + qz4.z*qz4.z));
        tile[i4 + 3] = make_float4(qx4.w, qy4.w, qz4.w, -0.5f * (qx4.w*qx4.w + qy4.w*qy4.w + qz4.w*qz4.w));
        __syncthreads();
        const float4* basep = tile + wave * 256;
#pragma unroll 4
        for (int i = 0; i < 256; ++i) {
            const float4 q = basep[i];
            float t = fmaf(q.x, px, fmaf(q.y, py, fmaf(q.z, pz, q.w)));
            insert_t(arr, t);
        }
    }
    __syncthreads();

    if (wave > 0) {
        float* dst = lists + ((wave - 1) * 64 + lane) * LSTR;
#pragma unroll
        for (int j = 0; j < KNN; ++j) dst[j] = arr[j];
    }
    __syncthreads();

    if (wave == 0) {
        for (int wsrc = 0; wsrc < WPB - 1; ++wsrc) {
            const float* src = lists + (wsrc * 64 + lane) * LSTR;
#pragma unroll
            for (int k = 0; k < KNN; ++k) insert_t(arr, src[k]);
        }
        finalize_row(arr, px, py, pz, row, lane, kmaxA, kminA, acc);
    }
}

__global__ __launch_bounds__(256) void out_kernel(
    const float* __restrict__ kmaxA, const float* __restrict__ kminA,
    const float* __restrict__ acc,
    const float* __restrict__ w, const float* __restrict__ gamma,
    const float* __restrict__ beta, float* __restrict__ out)
{
    const int r = blockIdx.x * 256 + threadIdx.x;
    const int b = r >> 13;
    const int n = r & (NPTS - 1);
    const float mu  = acc[0] * (1.0f / MTOTF);
    float var = acc[1] * (1.0f / MTOTF) - mu * mu;
    var = fmaxf(var, 0.f);
    const float kmax = kmaxA[r];
    const float kmin = kminA[r];
#pragma unroll
    for (int c = 0; c < 16; ++c) {
        const float wc = w[c];
        const float a = gamma[c] * wc * rsqrtf(wc * wc * var + 1e-5f);
        const float d = beta[c] - a * mu;
        float v = a * (a >= 0.f ? kmax : kmin) + d;
        v = (v >= 0.f) ? v : 0.2f * v;
        out[(b * 16 + c) * NPTS + n] = v;
    }
}

extern "C" void kernel_launch(void* const* d_in, const int* in_sizes, int n_in,
                              void* d_out, int out_size, void* d_ws, size_t ws_size,
                              hipStream_t stream)
{
    const float* x     = (const float*)d_in[0];
    const float* w     = (const float*)d_in[1];
    const float* gamma = (const float*)d_in[3];
    const float* beta  = (const float*)d_in[4];
    float* out = (float*)d_out;
    float* ws  = (float*)d_ws;

    float* kmaxA = ws;                                // NROWS
    float* kminA = ws + NROWS;                        // NROWS
    float* acc   = ws + 2 * NROWS;                    // 2 (+2 pad)
    float4* tile4 = (float4*)(ws + 2 * NROWS + 4);    // NROWS float4, 16B-aligned
    float* part  = ws + (2 * NROWS + 4) + 4 * NROWS;  // NROWS*2*KNN floats
    int* ticket  = (int*)(part + (size_t)NROWS * 2 * KNN);   // NGROUPS ints
    const size_t need_tile  = (size_t)(2 * NROWS + 4) * 4 + (size_t)NROWS * 16;
    const size_t need_fused = need_tile + (size_t)NROWS * 2 * KNN * 4
                              + (size_t)NGROUPS * 4;

    if (ws_size >= need_fused) {
        prep_kernel<<<NROWS / 256, 256, 0, stream>>>(x, tile4, acc, ticket);
        knn_fused_kernel<<<NGRID, BLK, 0, stream>>>(x, tile4, part, ticket,
                                                    kmaxA, kminA, acc);
        out_elem_kernel<<<(16 * NROWS) / 256, 256, 0, stream>>>(
            kmaxA, kminA, acc, w, gamma, beta, out);
    } else if (ws_size >= need_tile) {
        prep_kernel<<<NROWS / 256, 256, 0, stream>>>(x, tile4, acc, nullptr);
        knn_kernel<<<NROWS / 64, BLK, 0, stream>>>(x, tile4, kmaxA, kminA, acc);
        out_kernel<<<NROWS / 256, 256, 0, stream>>>(kmaxA, kminA, acc, w, gamma, beta, out);
    } else {
        prep_kernel<<<1, 256, 0, stream>>>(x, tile4, acc, nullptr); // only zeroes acc
        knn_kernel_lds<<<NROWS / 64, BLK, 0, stream>>>(x, kmaxA, kminA, acc);
        out_kernel<<<NROWS / 256, 256, 0, stream>>>(kmaxA, kminA, acc, w, gamma, beta, out);
    }
}

// Round 8
// 190.586 us; speedup vs baseline: 11.5113x; 1.2307x over previous
//
#include <hip/hip_runtime.h>
#include <stdint.h>

#define NPTS  8192
#define NB    4
#define KNN   20
#define NROWS (NB * NPTS)        // 32768
#define NGROUPS (NROWS / 64)     // 512 row-groups
#define MTOTF 655360.0f          // NROWS * KNN
#define WPB   8                  // waves per block; all waves share the same 64 rows
#define BLK   (WPB * 64)         // 512 threads
#define SLICE (NPTS / WPB)       // 1024 candidates per wave (round-1 fallback)
#define HALF  (NPTS / 2)         // 4096 candidates per split block
#define SLICE2 (HALF / WPB)      // 512 candidates per wave
#define LSTR  (KNN + 1)          // padded merge-list stride
#define CAP   12                 // round-1 fallback push-buffer slots
#define CAP2  16                 // split push-buffer slots
#define NGRID (2 * NGROUPS)      // 1024 blocks = 4/CU
#define NEG_INF -3.0e38f

__device__ __forceinline__ float med3f(float a, float b, float c) {
    return __builtin_amdgcn_fmed3f(a, b, c);
}

// Monotone float<->uint encoding so LDS atomicMax works as float-max (any sign).
__device__ __forceinline__ unsigned enc_f(float f) {
    unsigned u = __float_as_uint(f);
    return (u & 0x80000000u) ? ~u : (u | 0x80000000u);
}
__device__ __forceinline__ float dec_f(unsigned u) {
    return __uint_as_float((u & 0x80000000u) ? (u & 0x7fffffffu) : ~u);
}

// Insert t into descending top-KNN list (arr[0] = largest t = nearest point).
// Dropping off the bottom is always exact: 20 larger witnesses exist.
__device__ __forceinline__ void insert_t(float arr[KNN], float t) {
#pragma unroll
    for (int j = KNN - 1; j > 0; --j) arr[j] = med3f(t, arr[j - 1], arr[j]);
    arr[0] = fmaxf(arr[0], t);
}

// ---- round-1 fallback flush: fixed CAP, padded ----
__device__ __forceinline__ void flush_buf(float arr[KNN], int& cnt,
    const float* bufw, int lane, unsigned* threshS) {
#pragma unroll
    for (int s = 0; s < CAP; ++s) {
        const float v = bufw[s * 64 + lane];
        insert_t(arr, (s < cnt) ? v : NEG_INF);
    }
    cnt = 0;
    atomicMax(&threshS[lane], enc_f(arr[KNN - 1]));
}

// ---- chunk-skippable flush (4 slots per uniform test), verified in R2 ----
__device__ __forceinline__ void flush_dyn(float arr[KNN], int& cnt,
    const float* bufw, int lane, unsigned* threshS) {
#pragma unroll
    for (int s0 = 0; s0 < CAP2; s0 += 4) {
        if (__any(cnt > s0)) {
#pragma unroll
            for (int s = s0; s < s0 + 4; ++s) {
                const float v = bufw[s * 64 + lane];
                insert_t(arr, (s < cnt) ? v : NEG_INF);
            }
        }
    }
    cnt = 0;
    atomicMax(&threshS[lane], enc_f(arr[KNN - 1]));
}

// Shared tail: caller holds merged descending-t list for output row `row`.
// t = p.q - |q|^2/2, d2 = |p|^2 - 2t  (arr[0] = largest t = nearest).
__device__ __forceinline__ void finalize_row(
    float arr[KNN], float px, float py, float pz, int row, int lane,
    float* __restrict__ kmaxA, float* __restrict__ kminA, float* __restrict__ acc)
{
    const float pn2 = px * px + py * py + pz * pz;
    float sum = 0.f, sum2 = 0.f, dmin = 0.f, dmax = 0.f;
#pragma unroll
    for (int k = 0; k < KNN; ++k) {
        float d2 = fmaxf(fmaf(-2.f, arr[k], pn2), 0.f);
        float d = sqrtf(d2);
        sum += d; sum2 += d2;
        if (k == 0) dmin = d;
        dmax = d;
    }
    kmaxA[row] = dmax;
    kminA[row] = dmin;
#pragma unroll
    for (int o = 32; o; o >>= 1) {
        sum  += __shfl_down(sum,  o, 64);
        sum2 += __shfl_down(sum2, o, 64);
    }
    if (lane == 0) { atomicAdd(acc, sum); atomicAdd(acc + 1, sum2); }
}

// Prep: tile4[i] = (qx,qy,qz,-|q|^2/2); zero acc and the merge tickets.
__global__ __launch_bounds__(256) void prep_kernel(
    const float* __restrict__ x, float4* __restrict__ tile4,
    float* __restrict__ acc, int* __restrict__ ticket)
{
    const int i = blockIdx.x * 256 + threadIdx.x;    // 0..32767
    const int b = i >> 13;
    const int m = i & (NPTS - 1);
    const float* xb = x + b * 3 * NPTS;
    const float qx = xb[m], qy = xb[NPTS + m], qz = xb[2 * NPTS + m];
    tile4[i] = make_float4(qx, qy, qz, -0.5f * (qx * qx + qy * qy + qz * qz));
    if (i < 2) acc[i] = 0.f;
    if (ticket && i < NGROUPS) ticket[i] = 0;
}

// K1 (main): R2-verified half-scan + tree merge, then FENCE-FREE last-block
// merge: partials are published with agent-coherent relaxed atomic stores
// (sc1 — individually visible at the coherent point, NO buffer_wbl2/inv that
// would nuke co-resident blocks' L2 working set — the R7 49us regression).
// Ordering: sc1 stores -> s_waitcnt vmcnt(0) (wave-local) -> relaxed ticket
// add; second arrival reads partner via relaxed agent loads (can't hit a
// stale L2 line) and finalizes. No waiting -> deadlock-free, order-free.
__global__ __launch_bounds__(BLK, 8) void knn_fused_kernel(
    const float* __restrict__ x, const float4* __restrict__ tile4,
    float* __restrict__ part, int* __restrict__ ticket,
    float* __restrict__ kmaxA, float* __restrict__ kminA, float* __restrict__ acc)
{
    // 32 KB push buffers; tree-merge lists (4*64*21*4 = 21504 B) alias them.
    __shared__ float shmem[WPB * CAP2 * 64];
    __shared__ unsigned threshS[64];

    const int tid  = threadIdx.x;
    const int lane = tid & 63;
    const int wave = __builtin_amdgcn_readfirstlane(tid >> 6);
    const int rb   = blockIdx.x >> 1;        // row-group 0..511
    const int half = blockIdx.x & 1;         // candidate half
    const int rowBase = rb * 64;
    const int row  = rowBase + lane;
    const int b    = rowBase >> 13;
    const int n    = row & (NPTS - 1);
    const float* xb = x + b * 3 * NPTS;
    const float px = xb[n];
    const float py = xb[NPTS + n];
    const float pz = xb[2 * NPTS + n];

    if (tid < 64) threshS[tid] = enc_f(NEG_INF);

    float arr[KNN];
#pragma unroll
    for (int j = 0; j < KNN; ++j) arr[j] = NEG_INF;
    float* bufw = shmem + wave * (CAP2 * 64);
    __syncthreads();

    const float4* __restrict__ tp = tile4 + b * NPTS + half * HALF + wave * SLICE2;

    // Warm-up: private ladder over first 32; publish real 20-of-32 threshold.
#pragma unroll 8
    for (int i = 0; i < 32; ++i) {
        const float4 q = tp[i];
        insert_t(arr, fmaf(q.x, px, fmaf(q.y, py, fmaf(q.z, pz, q.w))));
    }
    atomicMax(&threshS[lane], enc_f(arr[KNN - 1]));

    int cnt = 0;
    for (int c = 1; c < SLICE2 / 32; ++c) {
        float th = dec_f(*(volatile unsigned*)(threshS + lane));
        const float4* tq = tp + c * 32;
        for (int g = 0; g < 8; ++g) {
#pragma unroll
            for (int u = 0; u < 4; ++u) {
                const float4 q = tq[g * 4 + u];      // wave-uniform -> scalar load
                const float t = fmaf(q.x, px, fmaf(q.y, py, fmaf(q.z, pz, q.w)));
                bufw[cnt * 64 + lane] = t;           // always-store (no branch)
                cnt += (t > th);
            }
            if (__any(cnt > CAP2 - 4)) {
                flush_dyn(arr, cnt, bufw, lane, threshS);
                th = dec_f(*(volatile unsigned*)(threshS + lane));
            }
        }
    }
    if (__any(cnt > 0)) flush_dyn(arr, cnt, bufw, lane, threshS);
    __syncthreads();   // all push-buffer use done before aliased list writes

    // Tree merge (verified R4/R6/R7): (0<-1)(2<-3)(4<-5)(6<-7) -> (0<-2)(4<-6) -> (0<-4)
    float* ml = shmem;
    if (wave & 1) {
        float* d = ml + (wave >> 1) * (64 * LSTR) + lane * LSTR;
#pragma unroll
        for (int k = 0; k < KNN; ++k) d[k] = arr[k];
    }
    __syncthreads();
    if (!(wave & 1)) {
        const float* s = ml + (wave >> 1) * (64 * LSTR) + lane * LSTR;
#pragma unroll
        for (int k = 0; k < KNN; ++k) insert_t(arr, s[k]);
    }
    __syncthreads();
    if (!(wave & 1) && (wave & 2)) {
        float* d = ml + (wave >> 2) * (64 * LSTR) + lane * LSTR;
#pragma unroll
        for (int k = 0; k < KNN; ++k) d[k] = arr[k];
    }
    __syncthreads();
    if ((wave & 3) == 0) {
        const float* s = ml + (wave >> 2) * (64 * LSTR) + lane * LSTR;
#pragma unroll
        for (int k = 0; k < KNN; ++k) insert_t(arr, s[k]);
    }
    __syncthreads();
    if (wave == 4) {
        float* d = ml + lane * LSTR;
#pragma unroll
        for (int k = 0; k < KNN; ++k) d[k] = arr[k];
    }
    __syncthreads();
    if (wave == 0) {
        const float* s = ml + lane * LSTR;
#pragma unroll
        for (int k = 0; k < KNN; ++k) insert_t(arr, s[k]);

        // publish my sorted partial list: agent-coherent relaxed stores (sc1),
        // NO fence -> no wbl2/inv -> co-resident scanners keep their L2 set.
        float* dst = part + (row * 2 + half) * KNN;
#pragma unroll
        for (int k = 0; k < KNN; ++k)
            __hip_atomic_store(&dst[k], arr[k], __ATOMIC_RELAXED,
                               __HIP_MEMORY_SCOPE_AGENT);
        // wave-local wait: my sc1 stores are at the coherent point before the
        // ticket bump becomes visible.
        asm volatile("s_waitcnt vmcnt(0)" ::: "memory");

        int old = 0;
        if (lane == 0)
            old = __hip_atomic_fetch_add(&ticket[rb], 1, __ATOMIC_RELAXED,
                                         __HIP_MEMORY_SCOPE_AGENT);
        old = __shfl(old, 0, 64);
        if (old == 1) {                               // I'm second: partner done
            const float* srcp = part + (row * 2 + (half ^ 1)) * KNN;
#pragma unroll
            for (int k = 0; k < KNN; ++k) {
                const float v = __hip_atomic_load(&srcp[k], __ATOMIC_RELAXED,
                                                  __HIP_MEMORY_SCOPE_AGENT);
                insert_t(arr, v);
            }
            finalize_row(arr, px, py, pz, row, lane, kmaxA, kminA, acc);
        }
    }
}

// K2: output, one element per thread (8192 waves -> latency well hidden).
__global__ __launch_bounds__(256) void out_elem_kernel(
    const float* __restrict__ kmaxA, const float* __restrict__ kminA,
    const float* __restrict__ acc,
    const float* __restrict__ w, const float* __restrict__ gamma,
    const float* __restrict__ beta, float* __restrict__ out)
{
    const int T = blockIdx.x * 256 + threadIdx.x;    // 0..524287 = (b*16+c)*NPTS+n
    const int n  = T & (NPTS - 1);
    const int bc = T >> 13;
    const int c  = bc & 15;
    const int b  = bc >> 4;
    const float mu  = acc[0] * (1.0f / MTOTF);
    float var = acc[1] * (1.0f / MTOTF) - mu * mu;
    var = fmaxf(var, 0.f);
    const float wc = w[c];
    const float a  = gamma[c] * wc * rsqrtf(wc * wc * var + 1e-5f);
    const float d  = beta[c] - a * mu;               // conv bias cancels inside BN
    const float km = (a >= 0.f) ? kmaxA[b * NPTS + n] : kminA[b * NPTS + n];
    float v = a * km + d;
    v = (v >= 0.f) ? v : 0.2f * v;
    out[T] = v;
}

// ===================== fallback path (small ws; verified R1 structure) ========

__global__ __launch_bounds__(BLK, 8) void knn_kernel(
    const float* __restrict__ x, const float4* __restrict__ tile4,
    float* __restrict__ kmaxA, float* __restrict__ kminA, float* __restrict__ acc)
{
    __shared__ float shmem[(WPB - 1) * 64 * LSTR];
    __shared__ unsigned threshS[64];

    const int tid  = threadIdx.x;
    const int lane = tid & 63;
    const int wave = __builtin_amdgcn_readfirstlane(tid >> 6);
    const int rowBase = blockIdx.x * 64;
    const int row  = rowBase + lane;
    const int b    = rowBase >> 13;
    const int n    = row & (NPTS - 1);
    const float* xb = x + b * 3 * NPTS;
    const float px = xb[n];
    const float py = xb[NPTS + n];
    const float pz = xb[2 * NPTS + n];

    if (tid < 64) threshS[tid] = enc_f(NEG_INF);

    float arr[KNN];
#pragma unroll
    for (int j = 0; j < KNN; ++j) arr[j] = NEG_INF;
    float* bufw = shmem + wave * (CAP * 64);
    int cnt = 0;
    __syncthreads();

    const float4* __restrict__ tp = tile4 + b * NPTS + wave * SLICE;
    float th = NEG_INF;
    for (int c = 0; c < SLICE / 32; ++c) {
        th = dec_f(*(volatile unsigned*)(threshS + lane));
        const float4* tq = tp + c * 32;
        for (int g = 0; g < 8; ++g) {
#pragma unroll
            for (int u = 0; u < 4; ++u) {
                const float4 q = tq[g * 4 + u];
                const float t = fmaf(q.x, px, fmaf(q.y, py, fmaf(q.z, pz, q.w)));
                if (t > th) { bufw[cnt * 64 + lane] = t; ++cnt; }
            }
            if (__any(cnt > CAP - 4)) {
                flush_buf(arr, cnt, bufw, lane, threshS);
                th = dec_f(*(volatile unsigned*)(threshS + lane));
            }
        }
    }
    if (__any(cnt > 0)) flush_buf(arr, cnt, bufw, lane, threshS);
    __syncthreads();

    if (wave > 0) {
        float* dst = shmem + ((wave - 1) * 64 + lane) * LSTR;
#pragma unroll
        for (int j = 0; j < KNN; ++j) dst[j] = arr[j];
    }
    __syncthreads();

    if (wave == 0) {
        for (int wsrc = 0; wsrc < WPB - 1; ++wsrc) {
            const float* src = shmem + (wsrc * 64 + lane) * LSTR;
#pragma unroll
            for (int k = 0; k < KNN; ++k) insert_t(arr, src[k]);
        }
        finalize_row(arr, px, py, pz, row, lane, kmaxA, kminA, acc);
    }
}

__global__ __launch_bounds__(BLK) void knn_kernel_lds(
    const float* __restrict__ x,
    float* __restrict__ kmaxA, float* __restrict__ kminA, float* __restrict__ acc)
{
    __shared__ float4 tile[2048];
    __shared__ float  lists[(WPB - 1) * 64 * LSTR];

    const int tid  = threadIdx.x;
    const int lane = tid & 63;
    const int wave = tid >> 6;
    const int rowBase = blockIdx.x * 64;
    const int row  = rowBase + lane;
    const int b    = rowBase >> 13;
    const int n    = row & (NPTS - 1);
    const float* xb = x + b * 3 * NPTS;
    const float px = xb[n];
    const float py = xb[NPTS + n];
    const float pz = xb[2 * NPTS + n];

    float arr[KNN];
#pragma unroll
    for (int j = 0; j < KNN; ++j) arr[j] = NEG_INF;

    for (int t0 = 0; t0 < NPTS; t0 += 2048) {
        __syncthreads();
        const int i4 = tid * 4;
        const float4 qx4 = *(const float4*)(xb + t0 + i4);
        const float4 qy4 = *(const float4*)(xb + NPTS + t0 + i4);
        const float4 qz4 = *(const float4*)(xb + 2 * NPTS + t0 + i4);
        tile[i4 + 0] = make_float4(qx4.x, qy4.x, qz4.x, -0.5f * (qx4.x*qx4.x + qy4.x*qy4.x + qz4.x*qz4.x));
        tile[i4 + 1] = make_float4(qx4.y, qy4.y, qz4.y, -0.5f * (qx4.y*qx4.y + qy4.y*qy4.y + qz4.y*qz4.y));
        tile[i4 + 2] = make_float4(qx4.z, qy4.z, qz4.z, -0.5f * (qx4.z*qx4.z + qy4.z*qy4.z + qz4.z*qz4.z));
        tile[i4 + 3] = make_float4(qx4.w, qy4.w, qz4.w, -0.5f * (qx4.w*qx4.w + qy4.w*qy4.w + qz4.w*qz4.w));
        __syncthreads();
        const float4* basep = tile + wave * 256;
#pragma unroll 4
        for (int i = 0; i < 256; ++i) {
            const float4 q = basep[i];
            float t = fmaf(q.x, px, fmaf(q.y, py, fmaf(q.z, pz, q.w)));
            insert_t(arr, t);
        }
    }
    __syncthreads();

    if (wave > 0) {
        float* dst = lists + ((wave - 1) * 64 + lane) * LSTR;
#pragma unroll
        for (int j = 0; j < KNN; ++j) dst[j] = arr[j];
    }
    __syncthreads();

    if (wave == 0) {
        for (int wsrc = 0; wsrc < WPB - 1; ++wsrc) {
            const float* src = lists + (wsrc * 64 + lane) * LSTR;
#pragma unroll
            for (int k = 0; k < KNN; ++k) insert_t(arr, src[k]);
        }
        finalize_row(arr, px, py, pz, row, lane, kmaxA, kminA, acc);
    }
}

__global__ __launch_bounds__(256) void out_kernel(
    const float* __restrict__ kmaxA, const float* __restrict__ kminA,
    const float* __restrict__ acc,
    const float* __restrict__ w, const float* __restrict__ gamma,
    const float* __restrict__ beta, float* __restrict__ out)
{
    const int r = blockIdx.x * 256 + threadIdx.x;
    const int b = r >> 13;
    const int n = r & (NPTS - 1);
    const float mu  = acc[0] * (1.0f / MTOTF);
    float var = acc[1] * (1.0f / MTOTF) - mu * mu;
    var = fmaxf(var, 0.f);
    const float kmax = kmaxA[r];
    const float kmin = kminA[r];
#pragma unroll
    for (int c = 0; c < 16; ++c) {
        const float wc = w[c];
        const float a = gamma[c] * wc * rsqrtf(wc * wc * var + 1e-5f);
        const float d = beta[c] - a * mu;
        float v = a * (a >= 0.f ? kmax : kmin) + d;
        v = (v >= 0.f) ? v : 0.2f * v;
        out[(b * 16 + c) * NPTS + n] = v;
    }
}

extern "C" void kernel_launch(void* const* d_in, const int* in_sizes, int n_in,
                              void* d_out, int out_size, void* d_ws, size_t ws_size,
                              hipStream_t stream)
{
    const float* x     = (const float*)d_in[0];
    const float* w     = (const float*)d_in[1];
    const float* gamma = (const float*)d_in[3];
    const float* beta  = (const float*)d_in[4];
    float* out = (float*)d_out;
    float* ws  = (float*)d_ws;

    float* kmaxA = ws;                                // NROWS
    float* kminA = ws + NROWS;                        // NROWS
    float* acc   = ws + 2 * NROWS;                    // 2 (+2 pad)
    float4* tile4 = (float4*)(ws + 2 * NROWS + 4);    // NROWS float4, 16B-aligned
    float* part  = ws + (2 * NROWS + 4) + 4 * NROWS;  // NROWS*2*KNN floats
    int* ticket  = (int*)(part + (size_t)NROWS * 2 * KNN);   // NGROUPS ints
    const size_t need_tile  = (size_t)(2 * NROWS + 4) * 4 + (size_t)NROWS * 16;
    const size_t need_fused = need_tile + (size_t)NROWS * 2 * KNN * 4
                              + (size_t)NGROUPS * 4;

    if (ws_size >= need_fused) {
        prep_kernel<<<NROWS / 256, 256, 0, stream>>>(x, tile4, acc, ticket);
        knn_fused_kernel<<<NGRID, BLK, 0, stream>>>(x, tile4, part, ticket,
                                                    kmaxA, kminA, acc);
        out_elem_kernel<<<(16 * NROWS) / 256, 256, 0, stream>>>(
            kmaxA, kminA, acc, w, gamma, beta, out);
    } else if (ws_size >= need_tile) {
        prep_kernel<<<NROWS / 256, 256, 0, stream>>>(x, tile4, acc, nullptr);
        knn_kernel<<<NROWS / 64, BLK, 0, stream>>>(x, tile4, kmaxA, kminA, acc);
        out_kernel<<<NROWS / 256, 256, 0, stream>>>(kmaxA, kminA, acc, w, gamma, beta, out);
    } else {
        prep_kernel<<<1, 256, 0, stream>>>(x, tile4, acc, nullptr); // only zeroes acc
        knn_kernel_lds<<<NROWS / 64, BLK, 0, stream>>>(x, kmaxA, kminA, acc);
        out_kernel<<<NROWS / 256, 256, 0, stream>>>(kmaxA, kminA, acc, w, gamma, beta, out);
    }
}